// Round 15
// baseline (4429.478 us; speedup 1.0000x reference)
//
#include <hip/hip_runtime.h>
#include <hip/hip_bf16.h>

#define B_   64
#define T_   2048
#define H_   128
#define G_   384      // 3*H
#define D0_  18
#define WIN  4
#define RING 8
#define NW   (T_ / WIN)   // 512

typedef __hip_bfloat16 bf16;
typedef __attribute__((ext_vector_type(4))) float f32x4;
typedef __attribute__((ext_vector_type(8))) short s16x8;

#define LOG2E 1.4426950408889634f
__device__ __forceinline__ float sigf(float x) {
    return __builtin_amdgcn_rcpf(1.0f + __builtin_amdgcn_exp2f(-LOG2E * x));
}
__device__ __forceinline__ float tanhf_(float x) {
    return 1.0f - 2.0f * __builtin_amdgcn_rcpf(1.0f + __builtin_amdgcn_exp2f((2.0f * LOG2E) * x));
}
__device__ __forceinline__ short f2bs(float v) {
    bf16 b = __float2bfloat16(v);
    return *reinterpret_cast<short*>(&b);
}
__device__ __forceinline__ unsigned short f2bu(float v) {
    bf16 b = __float2bfloat16(v);
    return *reinterpret_cast<unsigned short*>(&b);
}
#define MFMA16(A, B, C) __builtin_amdgcn_mfma_f32_16x16x32_bf16((A), (B), (C), 0, 0, 0)

// Distributed flag barrier: wave wv stores flags[wv]=tgt (plain ds_write,
// ordered after its h' ds_writes by DS in-order execution — validated R13);
// each wave polls all 4 flags (parallel ds_read_b32, no atomic serialization).
__device__ __forceinline__ void flag_sync(volatile unsigned* flags, int wv,
                                          int lane, unsigned tgt) {
    __asm__ volatile("" ::: "memory");
    if (lane == 0) flags[wv] = tgt;
    for (;;) {
        const unsigned f0 = flags[0], f1 = flags[1];
        const unsigned f2 = flags[2], f3 = flags[3];
        const unsigned mn = min(min(f0, f1), min(f2, f3));
        if (mn >= tgt) break;
    }
    __asm__ volatile("" ::: "memory");
}

// h ring slot: B-frag order (R14). short idx = kt*512 + l*8 + i holds
// h[k = kt*32 + (l>>4)*8 + i][m = l&15]. Reads conflict-free b128 at lane*16B.
// Write pos for (jt, quad, col, 4 r's): one b64 at
//   (jt>>1)*512 + ((((jt<<1)+(quad>>1))&3)*16 + col)*8 + (quad&1)*4.

// ---------------------------------------------------------------------------
// Layer 0 scan: 8 WGs x 256 thr (4 waves, 1/SIMD; LDS-padded to 1 WG/CU).
// Wave wv owns j-tiles {2wv, 2wv+1}: 24 h-MFMAs + 6 x-MFMAs per step.
// ---------------------------------------------------------------------------
__global__ __launch_bounds__(256, 1) void gru_l0_mfma(
    const float* __restrict__ x,
    const float* __restrict__ wih_f, const float* __restrict__ whh_f,
    const float* __restrict__ bih_f, const float* __restrict__ bhh_f,
    const float* __restrict__ wih_r, const float* __restrict__ whh_r,
    const float* __restrict__ bih_r, const float* __restrict__ bhh_r,
    bf16* __restrict__ l0h)
{
    __shared__ __align__(16) bf16 hring[RING][2048];
    __shared__ __align__(16) bf16 xbuf[2][WIN][512];
    __shared__ volatile unsigned flags[4];
    __shared__ char ldspad[42000];     // force 1 WG/CU

    const int bx   = blockIdx.x;
    const int dir  = bx >> 2;
    const int bg   = bx & 3;
    const int b0   = bg * 16;
    const int tid  = threadIdx.x;
    const int lane = tid & 63;
    const int wv   = tid >> 6;       // 0..3
    const int col  = lane & 15;
    const int quad = lane >> 4;

    if (tid == 0) ((volatile char*)ldspad)[0] = 1;

    const float* Wih = dir ? wih_r : wih_f;
    const float* Whh = dir ? whh_r : whh_f;
    const float* Bih = dir ? bih_r : bih_f;
    const float* Bhh = dir ? bhh_r : bhh_f;

    // A-frags + seeds per owned j-tile
    s16x8 wfr[2][3][4], wxf[2][3];
    f32x4 sR[2], sZ[2], sX[2], sN[2];
    int woff[2];
    #pragma unroll
    for (int u = 0; u < 2; ++u) {
        const int jt = wv * 2 + u;
        #pragma unroll
        for (int g = 0; g < 3; ++g) {
            const float* wrow = Whh + (size_t)(g * H_ + jt * 16 + col) * H_;
            #pragma unroll
            for (int kt = 0; kt < 4; ++kt) {
                const float* p = wrow + kt * 32 + quad * 8;
                s16x8 f;
                #pragma unroll
                for (int i = 0; i < 8; ++i) f[i] = f2bs(p[i]);
                wfr[u][g][kt] = f;
            }
            const float* xrow = Wih + (size_t)(g * H_ + jt * 16 + col) * D0_;
            s16x8 fx;
            #pragma unroll
            for (int i = 0; i < 8; ++i) {
                const int k = quad * 8 + i;
                fx[i] = (k < D0_) ? f2bs(xrow[k]) : (short)0;
            }
            wxf[u][g] = fx;
        }
        #pragma unroll
        for (int r = 0; r < 4; ++r) {
            const int j = jt * 16 + quad * 4 + r;
            sR[u][r] = Bih[j]        + Bhh[j];
            sZ[u][r] = Bih[H_ + j]   + Bhh[H_ + j];
            sX[u][r] = Bih[2*H_ + j];
            sN[u][r] = Bhh[2*H_ + j];
        }
        woff[u] = (jt >> 1) * 512 + ((((jt << 1) + (quad >> 1)) & 3) * 16 + col) * 8
                + (quad & 1) * 4;
    }
    const f32x4 z4 = (f32x4){0.f, 0.f, 0.f, 0.f};

    for (int i = tid; i < 2048; i += 256) hring[0][i] = __float2bfloat16(0.0f);
    if (tid < 4) flags[tid] = 0;
    #pragma unroll
    for (int k = 0; k < 8; ++k) {
        const int i = tid + k * 256;
        const int si = i >> 9, rem = i & 511;
        const int m = (rem >> 5) & 15, c = rem & 31;
        const int t = dir ? (T_ - 1 - si) : si;
        const float v = (c < D0_) ? x[((size_t)(b0 + m) * T_ + t) * D0_ + c] : 0.0f;
        xbuf[0][si][((c >> 3) * 16 + m) * 8 + (c & 7)] = __float2bfloat16(v);
    }
    __syncthreads();

    float hprev[2][4] = {{0.f,0.f,0.f,0.f},{0.f,0.f,0.f,0.f}};
    float xv[8];

    for (int w = 0; w < NW; ++w) {
        const int par = w & 1;
        s16x8 axf[WIN];
        #pragma unroll
        for (int si = 0; si < WIN; ++si)
            axf[si] = *(const s16x8*)&xbuf[par][si][lane * 8];

        #pragma unroll
        for (int si = 0; si < WIN; ++si) {
            const int s  = w * WIN + si;
            const int rb = s & (RING - 1);
            const int wb = (s + 1) & (RING - 1);

            s16x8 hfr[4];
            #pragma unroll
            for (int kt = 0; kt < 4; ++kt)
                hfr[kt] = *(const s16x8*)&hring[rb][kt * 512 + lane * 8];

            // x-MFMAs (independent of ring read) fill ds_read latency
            f32x4 aR1[2], aZ1[2], aX[2];
            #pragma unroll
            for (int u = 0; u < 2; ++u) {
                aR1[u] = MFMA16(wxf[u][0], axf[si], z4);
                aZ1[u] = MFMA16(wxf[u][1], axf[si], z4);
                aX[u]  = MFMA16(wxf[u][2], axf[si], sX[u]);
            }

            f32x4 aR0[2], aZ0[2], aN0[2], aN1[2];
            #pragma unroll
            for (int u = 0; u < 2; ++u) {
                aR0[u] = MFMA16(wfr[u][0][0], hfr[0], sR[u]);
                aZ0[u] = MFMA16(wfr[u][1][0], hfr[0], sZ[u]);
                aN0[u] = MFMA16(wfr[u][2][0], hfr[0], sN[u]);
                aR1[u] = MFMA16(wfr[u][0][2], hfr[2], aR1[u]);
                aZ1[u] = MFMA16(wfr[u][1][2], hfr[2], aZ1[u]);
                aN1[u] = MFMA16(wfr[u][2][2], hfr[2], z4);
                aR0[u] = MFMA16(wfr[u][0][1], hfr[1], aR0[u]);
                aZ0[u] = MFMA16(wfr[u][1][1], hfr[1], aZ0[u]);
                aN0[u] = MFMA16(wfr[u][2][1], hfr[1], aN0[u]);
                aR1[u] = MFMA16(wfr[u][0][3], hfr[3], aR1[u]);
                aZ1[u] = MFMA16(wfr[u][1][3], hfr[3], aZ1[u]);
                aN1[u] = MFMA16(wfr[u][2][3], hfr[3], aN1[u]);
            }

            // prefetch next window's x in the MFMA shadow
            if (si == 0 && w + 1 < NW) {
                #pragma unroll
                for (int k = 0; k < 8; ++k) {
                    const int i = tid + k * 256;
                    const int sj = i >> 9, rem = i & 511;
                    const int m = (rem >> 5) & 15, c = rem & 31;
                    const int s2 = (w + 1) * WIN + sj;
                    const int t2 = dir ? (T_ - 1 - s2) : s2;
                    xv[k] = (c < D0_) ? x[((size_t)(b0 + m) * T_ + t2) * D0_ + c] : 0.0f;
                }
            }

            #pragma unroll
            for (int u = 0; u < 2; ++u) {
                unsigned short hb[4];
                #pragma unroll
                for (int r = 0; r < 4; ++r) {
                    const float rg = sigf(aR0[u][r] + aR1[u][r]);
                    const float zg = sigf(aZ0[u][r] + aZ1[u][r]);
                    const float ng = tanhf_(fmaf(rg, aN0[u][r] + aN1[u][r], aX[u][r]));
                    const float hn = fmaf(zg, hprev[u][r] - ng, ng);
                    hprev[u][r] = hn;
                    hb[r] = f2bu(hn);
                }
                uint2 wv2;
                wv2.x = (unsigned)hb[0] | ((unsigned)hb[1] << 16);
                wv2.y = (unsigned)hb[2] | ((unsigned)hb[3] << 16);
                *(uint2*)&hring[wb][woff[u]] = wv2;
            }

            if (si == 3 && w + 1 < NW) {
                #pragma unroll
                for (int k = 0; k < 8; ++k) {
                    const int i = tid + k * 256;
                    const int sj = i >> 9, rem = i & 511;
                    const int m = (rem >> 5) & 15, c = rem & 31;
                    xbuf[par ^ 1][sj][((c >> 3) * 16 + m) * 8 + (c & 7)] =
                        __float2bfloat16(xv[k]);
                }
            }
            flag_sync(flags, wv, lane, (unsigned)(s + 1));
        }

        // flush h history (coalesced; fire-and-forget)
        #pragma unroll
        for (int k = 0; k < 4; ++k) {
            const int c  = tid + k * 256;
            const int dt = c >> 8, m = (c >> 4) & 15, jo = c & 15;
            const int s  = w * WIN + dt;
            const int t  = dir ? (T_ - 1 - s) : s;
            const uint4 v = *(const uint4*)
                &hring[(s + 1) & (RING - 1)][(jo >> 2) * 512 + ((jo & 3) * 16 + m) * 8];
            *(uint4*)(l0h + ((size_t)(b0 + m) * T_ + t) * 256 + dir * H_ + jo * 8) = v;
        }
    }
}

// ---------------------------------------------------------------------------
// xg GEMM (both dirs, grid.z): D[j'][bt] = W_A . l0h_B + bias, emitted in
// scan C-layout xgC[bg][t][g][jt][lane] (uint2 = 4 consecutive j's, bf16).
// ---------------------------------------------------------------------------
__global__ __launch_bounds__(256, 2) void xg_gemm_mfma(
    const bf16* __restrict__ A,
    const float* __restrict__ w_f, const float* __restrict__ w_r,
    const float* __restrict__ bi_f, const float* __restrict__ bi_r,
    const float* __restrict__ bh_f, const float* __restrict__ bh_r,
    bf16* __restrict__ xg_f, bf16* __restrict__ xg_r)
{
    __shared__ short As[128 * 40];
    __shared__ short Ws[128 * 40];
    __shared__ float Bias_s[128];

    const int dir  = blockIdx.z;
    const float* W   = dir ? w_r : w_f;
    const float* bi  = dir ? bi_r : bi_f;
    const float* bh  = dir ? bh_r : bh_f;
    bf16* xg         = dir ? xg_r : xg_f;

    const int tid  = threadIdx.x;
    const int lane = tid & 63;
    const int wv   = tid >> 6;
    const int col  = lane & 15;
    const int quad = lane >> 4;
    const int n0   = blockIdx.x * 128;        // bt base (single batch)
    const int g    = blockIdx.y;              // gate block
    const int m0   = g * 128;

    if (tid < 128) {
        const int n = m0 + tid;
        Bias_s[tid] = bi[n] + ((n < 2 * H_) ? bh[n] : 0.0f);
    }

    f32x4 acc[2][8];
    #pragma unroll
    for (int mt = 0; mt < 2; ++mt)
        #pragma unroll
        for (int nt = 0; nt < 8; ++nt) acc[mt][nt] = (f32x4){0.f, 0.f, 0.f, 0.f};

    for (int k0 = 0; k0 < 256; k0 += 32) {
        #pragma unroll
        for (int i = 0; i < 2; ++i) {
            const int c = tid + i * 256;
            const int row = c >> 2, q4 = c & 3;
            *(uint4*)&As[row * 40 + q4 * 8] =
                *(const uint4*)(A + (size_t)(n0 + row) * 256 + k0 + q4 * 8);
        }
        #pragma unroll
        for (int i = 0; i < 4; ++i) {
            const int c = tid + i * 256;
            const int row = c >> 3, q = c & 7;
            const float4 v = *(const float4*)(W + (size_t)(m0 + row) * 256 + k0 + q * 4);
            ushort4 u;
            u.x = f2bu(v.x); u.y = f2bu(v.y); u.z = f2bu(v.z); u.w = f2bu(v.w);
            *(ushort4*)&Ws[row * 40 + q * 4] = u;
        }
        __syncthreads();

        s16x8 wfr[2], hfr[8];
        #pragma unroll
        for (int mt = 0; mt < 2; ++mt)
            wfr[mt] = *(const s16x8*)&Ws[(wv * 32 + mt * 16 + col) * 40 + quad * 8];
        #pragma unroll
        for (int nt = 0; nt < 8; ++nt)
            hfr[nt] = *(const s16x8*)&As[(nt * 16 + col) * 40 + quad * 8];

        #pragma unroll
        for (int mt = 0; mt < 2; ++mt)
            #pragma unroll
            for (int nt = 0; nt < 8; ++nt)
                acc[mt][nt] = MFMA16(wfr[mt], hfr[nt], acc[mt][nt]);
        __syncthreads();
    }

    const int batch = n0 >> 11;
    const int bg = batch >> 4, cm = batch & 15;
    #pragma unroll
    for (int mt = 0; mt < 2; ++mt) {
        const int jt = wv * 2 + mt;
        float bv[4];
        #pragma unroll
        for (int r = 0; r < 4; ++r)
            bv[r] = Bias_s[wv * 32 + mt * 16 + quad * 4 + r];
        #pragma unroll
        for (int nt = 0; nt < 8; ++nt) {
            const int t = (n0 & 2047) + nt * 16 + col;
            uint2 o;
            o.x = (unsigned)f2bu(acc[mt][nt][0] + bv[0]) |
                  ((unsigned)f2bu(acc[mt][nt][1] + bv[1]) << 16);
            o.y = (unsigned)f2bu(acc[mt][nt][2] + bv[2]) |
                  ((unsigned)f2bu(acc[mt][nt][3] + bv[3]) << 16);
            const size_t idx = ((((size_t)bg * T_ + t) * 3 + g) * 8 + jt) * 64
                             + quad * 16 + cm;
            ((uint2*)xg)[idx] = o;
        }
    }
}

// ---------------------------------------------------------------------------
// Layer 1 scan: 4 waves x 2 j-tiles; xg register-prefetched per window.
// ---------------------------------------------------------------------------
__global__ __launch_bounds__(256, 1) void gru_l1_mfma(
    const bf16* __restrict__ xg_f, const bf16* __restrict__ xg_r,
    const float* __restrict__ whh_f, const float* __restrict__ bhh_f,
    const float* __restrict__ whh_r, const float* __restrict__ bhh_r,
    bf16* __restrict__ l1h, int fixed_dir)
{
    __shared__ __align__(16) bf16 hring[RING][2048];
    __shared__ volatile unsigned flags[4];
    __shared__ char ldspad[49200];     // force 1 WG/CU

    const int bx   = blockIdx.x;
    const int dir  = (fixed_dir >= 0) ? fixed_dir : (bx >> 2);
    const int bg   = bx & 3;
    const int b0   = bg * 16;
    const int tid  = threadIdx.x;
    const int lane = tid & 63;
    const int wv   = tid >> 6;
    const int col  = lane & 15;
    const int quad = lane >> 4;

    if (tid == 0) ((volatile char*)ldspad)[0] = 1;

    const bf16*  XG  = dir ? xg_r : xg_f;
    const float* Whh = dir ? whh_r : whh_f;
    const float* Bhh = dir ? bhh_r : bhh_f;

    s16x8 wfr[2][3][4];
    f32x4 sN[2];
    int woff[2];
    #pragma unroll
    for (int u = 0; u < 2; ++u) {
        const int jt = wv * 2 + u;
        #pragma unroll
        for (int g = 0; g < 3; ++g) {
            const float* wrow = Whh + (size_t)(g * H_ + jt * 16 + col) * H_;
            #pragma unroll
            for (int kt = 0; kt < 4; ++kt) {
                const float* p = wrow + kt * 32 + quad * 8;
                s16x8 f;
                #pragma unroll
                for (int i = 0; i < 8; ++i) f[i] = f2bs(p[i]);
                wfr[u][g][kt] = f;
            }
        }
        #pragma unroll
        for (int r = 0; r < 4; ++r)
            sN[u][r] = Bhh[2*H_ + jt * 16 + quad * 4 + r];
        woff[u] = (jt >> 1) * 512 + ((((jt << 1) + (quad >> 1)) & 3) * 16 + col) * 8
                + (quad & 1) * 4;
    }
    const f32x4 z4 = (f32x4){0.f, 0.f, 0.f, 0.f};

    for (int i = tid; i < 2048; i += 256) hring[0][i] = __float2bfloat16(0.0f);
    if (tid < 4) flags[tid] = 0;

    const uint2* xgb = (const uint2*)XG + ((size_t)bg * T_) * 3 * 8 * 64;
    const int lidx0 = (wv * 2 + 0) * 64 + lane;
    const int lidx1 = (wv * 2 + 1) * 64 + lane;

    uint2 xcur[WIN][2][3], xnxt[WIN][2][3];
    #pragma unroll
    for (int si = 0; si < WIN; ++si) {
        const int t = dir ? (T_ - 1 - si) : si;
        #pragma unroll
        for (int g = 0; g < 3; ++g) {
            xcur[si][0][g] = xgb[((size_t)t * 3 + g) * 512 + lidx0];
            xcur[si][1][g] = xgb[((size_t)t * 3 + g) * 512 + lidx1];
        }
    }
    __syncthreads();

    float hprev[2][4] = {{0.f,0.f,0.f,0.f},{0.f,0.f,0.f,0.f}};

    for (int w = 0; w < NW; ++w) {
        #pragma unroll
        for (int si = 0; si < WIN; ++si) {
            const int s  = w * WIN + si;
            const int rb = s & (RING - 1);
            const int wb = (s + 1) & (RING - 1);

            s16x8 hfr[4];
            #pragma unroll
            for (int kt = 0; kt < 4; ++kt)
                hfr[kt] = *(const s16x8*)&hring[rb][kt * 512 + lane * 8];

            // unpack seeds while ds_reads are in flight
            f32x4 seedR[2], seedZ[2];
            float xnf[2][4];
            #pragma unroll
            for (int u = 0; u < 2; ++u) {
                const uint2 xr2 = xcur[si][u][0], xz2 = xcur[si][u][1],
                            xn2 = xcur[si][u][2];
                seedR[u] = (f32x4){
                    __uint_as_float(xr2.x << 16), __uint_as_float(xr2.x & 0xffff0000u),
                    __uint_as_float(xr2.y << 16), __uint_as_float(xr2.y & 0xffff0000u)};
                seedZ[u] = (f32x4){
                    __uint_as_float(xz2.x << 16), __uint_as_float(xz2.x & 0xffff0000u),
                    __uint_as_float(xz2.y << 16), __uint_as_float(xz2.y & 0xffff0000u)};
                xnf[u][0] = __uint_as_float(xn2.x << 16);
                xnf[u][1] = __uint_as_float(xn2.x & 0xffff0000u);
                xnf[u][2] = __uint_as_float(xn2.y << 16);
                xnf[u][3] = __uint_as_float(xn2.y & 0xffff0000u);
            }

            f32x4 aR0[2], aZ0[2], aN0[2], aR1[2], aZ1[2], aN1[2];
            #pragma unroll
            for (int u = 0; u < 2; ++u) {
                aR0[u] = MFMA16(wfr[u][0][0], hfr[0], seedR[u]);
                aZ0[u] = MFMA16(wfr[u][1][0], hfr[0], seedZ[u]);
                aN0[u] = MFMA16(wfr[u][2][0], hfr[0], sN[u]);
                aR1[u] = MFMA16(wfr[u][0][2], hfr[2], z4);
                aZ1[u] = MFMA16(wfr[u][1][2], hfr[2], z4);
                aN1[u] = MFMA16(wfr[u][2][2], hfr[2], z4);
                aR0[u] = MFMA16(wfr[u][0][1], hfr[1], aR0[u]);
                aZ0[u] = MFMA16(wfr[u][1][1], hfr[1], aZ0[u]);
                aN0[u] = MFMA16(wfr[u][2][1], hfr[1], aN0[u]);
                aR1[u] = MFMA16(wfr[u][0][3], hfr[3], aR1[u]);
                aZ1[u] = MFMA16(wfr[u][1][3], hfr[3], aZ1[u]);
                aN1[u] = MFMA16(wfr[u][2][3], hfr[3], aN1[u]);
            }

            if (si == 0 && w + 1 < NW) {
                #pragma unroll
                for (int sj = 0; sj < WIN; ++sj) {
                    const int s2 = (w + 1) * WIN + sj;
                    const int t2 = dir ? (T_ - 1 - s2) : s2;
                    #pragma unroll
                    for (int g = 0; g < 3; ++g) {
                        xnxt[sj][0][g] = xgb[((size_t)t2 * 3 + g) * 512 + lidx0];
                        xnxt[sj][1][g] = xgb[((size_t)t2 * 3 + g) * 512 + lidx1];
                    }
                }
            }

            #pragma unroll
            for (int u = 0; u < 2; ++u) {
                unsigned short hb[4];
                #pragma unroll
                for (int r = 0; r < 4; ++r) {
                    const float rg = sigf(aR0[u][r] + aR1[u][r]);
                    const float zg = sigf(aZ0[u][r] + aZ1[u][r]);
                    const float ng = tanhf_(fmaf(rg, aN0[u][r] + aN1[u][r], xnf[u][r]));
                    const float hn = fmaf(zg, hprev[u][r] - ng, ng);
                    hprev[u][r] = hn;
                    hb[r] = f2bu(hn);
                }
                uint2 wv2;
                wv2.x = (unsigned)hb[0] | ((unsigned)hb[1] << 16);
                wv2.y = (unsigned)hb[2] | ((unsigned)hb[3] << 16);
                *(uint2*)&hring[wb][woff[u]] = wv2;
            }

            flag_sync(flags, wv, lane, (unsigned)(s + 1));
        }

        #pragma unroll
        for (int k = 0; k < 4; ++k) {
            const int c  = tid + k * 256;
            const int dt = c >> 8, m = (c >> 4) & 15, jo = c & 15;
            const int s  = w * WIN + dt;
            const int t  = dir ? (T_ - 1 - s) : s;
            const uint4 v = *(const uint4*)
                &hring[(s + 1) & (RING - 1)][(jo >> 2) * 512 + ((jo & 3) * 16 + m) * 8];
            *(uint4*)(l1h + ((size_t)(b0 + m) * T_ + t) * 256 + dir * H_ + jo * 8) = v;
        }
        #pragma unroll
        for (int si = 0; si < WIN; ++si)
            #pragma unroll
            for (int u = 0; u < 2; ++u)
                #pragma unroll
                for (int g = 0; g < 3; ++g)
                    xcur[si][u][g] = xnxt[si][u][g];
    }
}

// ---------------------------------------------------------------------------
// FC epilogue: out[bt][c] = fc_b[c] + fc_w[c][:] . l1h[bt][:]
// ---------------------------------------------------------------------------
__global__ __launch_bounds__(256, 2) void fc_kernel(
    const bf16* __restrict__ h, const float* __restrict__ fcw,
    const float* __restrict__ fcb, float* __restrict__ out)
{
    __shared__ float w0[256], w1[256];
    const int tid = threadIdx.x;
    w0[tid] = fcw[tid];
    w1[tid] = fcw[256 + tid];
    __syncthreads();

    const size_t bt = (size_t)blockIdx.x * 256 + tid;
    const bf16* hp = h + bt * 256;
    float s0 = fcb[0], s1 = fcb[1];
    #pragma unroll 4
    for (int k8 = 0; k8 < 32; ++k8) {
        const uint4 u = *(const uint4*)(hp + k8 * 8);
        const unsigned uu[4] = {u.x, u.y, u.z, u.w};
        #pragma unroll
        for (int p = 0; p < 4; ++p) {
            const float v0 = __uint_as_float(uu[p] << 16);
            const float v1 = __uint_as_float(uu[p] & 0xffff0000u);
            const int k = k8 * 8 + p * 2;
            s0 = fmaf(w0[k], v0, s0);     s1 = fmaf(w1[k], v0, s1);
            s0 = fmaf(w0[k + 1], v1, s0); s1 = fmaf(w1[k + 1], v1, s1);
        }
    }
    out[bt * 2]     = s0;
    out[bt * 2 + 1] = s1;
}

extern "C" void kernel_launch(void* const* d_in, const int* in_sizes, int n_in,
                              void* d_out, int out_size, void* d_ws, size_t ws_size,
                              hipStream_t stream)
{
    if (n_in < 19) return;
    const float* x     = (const float*)d_in[0];
    const float* wih0  = (const float*)d_in[1];
    const float* whh0  = (const float*)d_in[2];
    const float* bih0  = (const float*)d_in[3];
    const float* bhh0  = (const float*)d_in[4];
    const float* wih0r = (const float*)d_in[5];
    const float* whh0r = (const float*)d_in[6];
    const float* bih0r = (const float*)d_in[7];
    const float* bhh0r = (const float*)d_in[8];
    const float* wih1  = (const float*)d_in[9];
    const float* whh1  = (const float*)d_in[10];
    const float* bih1  = (const float*)d_in[11];
    const float* bhh1  = (const float*)d_in[12];
    const float* wih1r = (const float*)d_in[13];
    const float* whh1r = (const float*)d_in[14];
    const float* bih1r = (const float*)d_in[15];
    const float* bhh1r = (const float*)d_in[16];
    const float* fcw   = (const float*)d_in[17];
    const float* fcb   = (const float*)d_in[18];
    float* out = (float*)d_out;

    const size_t nBT  = (size_t)B_ * T_;
    const size_t hh_b = nBT * 2 * H_ * sizeof(bf16);     // 64 MiB
    const size_t xg_b = nBT * G_ * sizeof(bf16);         // 96 MiB per dir
    const size_t xg_el = nBT * G_;

    if (ws_size >= hh_b + 2 * xg_b) {                    // 256 MiB path
        bf16* l0h = (bf16*)d_ws;
        bf16* xgf = (bf16*)((char*)d_ws + hh_b);
        bf16* xgr = xgf + xg_el;

        gru_l0_mfma<<<dim3(8), dim3(256), 0, stream>>>(
            x, wih0, whh0, bih0, bhh0, wih0r, whh0r, bih0r, bhh0r, l0h);
        xg_gemm_mfma<<<dim3(1024, 3, 2), dim3(256), 0, stream>>>(
            l0h, wih1, wih1r, bih1, bih1r, bhh1, bhh1r, xgf, xgr);
        gru_l1_mfma<<<dim3(8), dim3(256), 0, stream>>>(
            xgf, xgr, whh1, bhh1, whh1r, bhh1r, l0h, -1);   // l1h aliases l0h
        fc_kernel<<<dim3((int)(nBT / 256)), dim3(256), 0, stream>>>(l0h, fcw, fcb, out);
    } else if (ws_size >= 2 * hh_b + xg_b) {             // 224 MiB sequential
        bf16* l0h = (bf16*)d_ws;
        bf16* xg  = (bf16*)((char*)d_ws + hh_b);
        bf16* l1h = (bf16*)((char*)d_ws + hh_b + xg_b);

        gru_l0_mfma<<<dim3(8), dim3(256), 0, stream>>>(
            x, wih0, whh0, bih0, bhh0, wih0r, whh0r, bih0r, bhh0r, l0h);
        xg_gemm_mfma<<<dim3(1024, 3, 1), dim3(256), 0, stream>>>(
            l0h, wih1, wih1, bih1, bih1, bhh1, bhh1, xg, xg);
        gru_l1_mfma<<<dim3(4), dim3(256), 0, stream>>>(
            xg, xg, whh1, bhh1, whh1r, bhh1r, l1h, 0);
        xg_gemm_mfma<<<dim3(1024, 3, 1), dim3(256), 0, stream>>>(
            l0h, wih1r, wih1r, bih1r, bih1r, bhh1r, bhh1r, xg, xg);
        gru_l1_mfma<<<dim3(4), dim3(256), 0, stream>>>(
            xg, xg, whh1, bhh1, whh1r, bhh1r, l1h, 1);
        fc_kernel<<<dim3((int)(nBT / 256)), dim3(256), 0, stream>>>(l1h, fcw, fcb, out);
    }
}

// Round 16
// 4185.623 us; speedup vs baseline: 1.0583x; 1.0583x over previous
//
#include <hip/hip_runtime.h>
#include <hip/hip_bf16.h>

#define B_   64
#define T_   2048
#define H_   128
#define G_   384      // 3*H
#define D0_  18
#define WIN  4
#define RING 8
#define NW   (T_ / WIN)   // 512

typedef __hip_bfloat16 bf16;
typedef __attribute__((ext_vector_type(4))) float f32x4;
typedef __attribute__((ext_vector_type(8))) short s16x8;

#define LOG2E 1.4426950408889634f
__device__ __forceinline__ float sigf(float x) {
    return __builtin_amdgcn_rcpf(1.0f + __builtin_amdgcn_exp2f(-LOG2E * x));
}
__device__ __forceinline__ float tanhf_(float x) {
    return 1.0f - 2.0f * __builtin_amdgcn_rcpf(1.0f + __builtin_amdgcn_exp2f((2.0f * LOG2E) * x));
}
__device__ __forceinline__ short f2bs(float v) {
    bf16 b = __float2bfloat16(v);
    return *reinterpret_cast<short*>(&b);
}
__device__ __forceinline__ unsigned short f2bu(float v) {
    bf16 b = __float2bfloat16(v);
    return *reinterpret_cast<unsigned short*>(&b);
}
#define MFMA16(A, B, C) __builtin_amdgcn_mfma_f32_16x16x32_bf16((A), (B), (C), 0, 0, 0)

// Distributed 8-flag barrier (R16: isolates sync mechanism vs R14's atomic).
// Wave wv plain-stores flags[wv] (8 distinct banks, parallel, ordered after
// its h' ds_writes by DS in-order execution — validated R13). Poll reads all
// 8 (same-address broadcast per flag) and min-chains. No atomics.
__device__ __forceinline__ void flag_sync8(volatile unsigned* flags, int wv,
                                           int lane, unsigned tgt) {
    __asm__ volatile("" ::: "memory");
    if (lane == 0) flags[wv] = tgt;
    for (;;) {
        unsigned mn = flags[0];
        #pragma unroll
        for (int i = 1; i < 8; ++i) mn = min(mn, flags[i]);
        if (mn >= tgt) break;
    }
    __asm__ volatile("" ::: "memory");
}

// h ring slot: B-frag order (R14). short idx = kt*512 + l*8 + i holds
// h[k = kt*32 + (l>>4)*8 + i][m = l&15]. Reads conflict-free b128 at lane*16B.

// ---------------------------------------------------------------------------
// Layer 0 scan: gates D[j][m] = Whh_A . h_B (+ Wih_A . x_B). 8 WGs x 512 thr.
// ---------------------------------------------------------------------------
__global__ __launch_bounds__(512) void gru_l0_mfma(
    const float* __restrict__ x,
    const float* __restrict__ wih_f, const float* __restrict__ whh_f,
    const float* __restrict__ bih_f, const float* __restrict__ bhh_f,
    const float* __restrict__ wih_r, const float* __restrict__ whh_r,
    const float* __restrict__ bih_r, const float* __restrict__ bhh_r,
    bf16* __restrict__ l0h)
{
    __shared__ __align__(16) bf16 hring[RING][2048];
    __shared__ __align__(16) bf16 xbuf[2][WIN][512];   // B-frag order, k<32 pad
    __shared__ volatile unsigned flags[8];

    const int bx   = blockIdx.x;
    const int dir  = bx >> 2;
    const int bg   = bx & 3;
    const int b0   = bg * 16;
    const int tid  = threadIdx.x;
    const int lane = tid & 63;
    const int wv   = tid >> 6;       // = jt (j-tile)
    const int col  = lane & 15;
    const int quad = lane >> 4;

    const float* Wih = dir ? wih_r : wih_f;
    const float* Whh = dir ? whh_r : whh_f;
    const float* Bih = dir ? bih_r : bih_f;
    const float* Bhh = dir ? bhh_r : bhh_f;

    // A-frags: lane holds W[row = tile + col][k = kt*32 + quad*8 + i]
    s16x8 wfr[3][4], wxf[3];
    #pragma unroll
    for (int g = 0; g < 3; ++g) {
        const float* wrow = Whh + (size_t)(g * H_ + wv * 16 + col) * H_;
        #pragma unroll
        for (int kt = 0; kt < 4; ++kt) {
            const float* p = wrow + kt * 32 + quad * 8;
            s16x8 f;
            #pragma unroll
            for (int i = 0; i < 8; ++i) f[i] = f2bs(p[i]);
            wfr[g][kt] = f;
        }
        const float* xrow = Wih + (size_t)(g * H_ + wv * 16 + col) * D0_;
        s16x8 fx;
        #pragma unroll
        for (int i = 0; i < 8; ++i) {
            const int k = quad * 8 + i;
            fx[i] = (k < D0_) ? f2bs(xrow[k]) : (short)0;
        }
        wxf[g] = fx;
    }
    // per-r seeds: j = wv*16 + quad*4 + r
    f32x4 sR, sZ, sX, sN;
    #pragma unroll
    for (int r = 0; r < 4; ++r) {
        const int j = wv * 16 + quad * 4 + r;
        sR[r] = Bih[j]        + Bhh[j];
        sZ[r] = Bih[H_ + j]   + Bhh[H_ + j];
        sX[r] = Bih[2*H_ + j];
        sN[r] = Bhh[2*H_ + j];
    }
    const f32x4 z4 = (f32x4){0.f, 0.f, 0.f, 0.f};

    // h' write slot (B-frag position for j = wv*16+quad*4+r, m = col)
    const int wkt   = wv >> 1;
    const int wl    = (((wv << 1) + (quad >> 1)) & 3) * 16 + col;
    const int woff  = wkt * 512 + wl * 8 + (quad & 1) * 4;   // shorts

    for (int i = tid; i < 2048; i += 512) hring[0][i] = __float2bfloat16(0.0f);
    if (tid < 8) flags[tid] = 0;
    // stage x window 0 (B-frag order)
    #pragma unroll
    for (int k = 0; k < 4; ++k) {
        const int i = tid + k * 512;
        const int si = i >> 9, rem = i & 511;
        const int m = (rem >> 5) & 15, c = rem & 31;
        const int t = dir ? (T_ - 1 - si) : si;
        const float v = (c < D0_) ? x[((size_t)(b0 + m) * T_ + t) * D0_ + c] : 0.0f;
        xbuf[0][si][((c >> 3) * 16 + m) * 8 + (c & 7)] = __float2bfloat16(v);
    }
    __syncthreads();

    float hprev[4] = {0.f, 0.f, 0.f, 0.f};
    float xv[4];

    for (int w = 0; w < NW; ++w) {
        const int par = w & 1;
        s16x8 axf[WIN];
        #pragma unroll
        for (int si = 0; si < WIN; ++si)
            axf[si] = *(const s16x8*)&xbuf[par][si][lane * 8];

        #pragma unroll
        for (int si = 0; si < WIN; ++si) {
            const int s  = w * WIN + si;
            const int rb = s & (RING - 1);
            const int wb = (s + 1) & (RING - 1);

            // B-frag h reads: contiguous lane*16B per kt block (conflict-free)
            s16x8 hfr[4];
            #pragma unroll
            for (int kt = 0; kt < 4; ++kt)
                hfr[kt] = *(const s16x8*)&hring[rb][kt * 512 + lane * 8];

            // x-MFMAs fill the ds_read latency
            f32x4 aR1 = MFMA16(wxf[0], axf[si], z4);
            f32x4 aZ1 = MFMA16(wxf[1], axf[si], z4);
            f32x4 aX  = MFMA16(wxf[2], axf[si], sX);

            f32x4 aR0 = MFMA16(wfr[0][0], hfr[0], sR);
            f32x4 aZ0 = MFMA16(wfr[1][0], hfr[0], sZ);
            f32x4 aN0 = MFMA16(wfr[2][0], hfr[0], sN);
            aR1 = MFMA16(wfr[0][2], hfr[2], aR1);
            aZ1 = MFMA16(wfr[1][2], hfr[2], aZ1);
            f32x4 aN1 = MFMA16(wfr[2][2], hfr[2], z4);
            aR0 = MFMA16(wfr[0][1], hfr[1], aR0);
            aZ0 = MFMA16(wfr[1][1], hfr[1], aZ0);
            aN0 = MFMA16(wfr[2][1], hfr[1], aN0);
            aR1 = MFMA16(wfr[0][3], hfr[3], aR1);
            aZ1 = MFMA16(wfr[1][3], hfr[3], aZ1);
            aN1 = MFMA16(wfr[2][3], hfr[3], aN1);

            // prefetch next window's x in the MFMA shadow
            if (si == 0 && w + 1 < NW) {
                #pragma unroll
                for (int k = 0; k < 4; ++k) {
                    const int i = tid + k * 512;
                    const int sj = i >> 9, rem = i & 511;
                    const int m = (rem >> 5) & 15, c = rem & 31;
                    const int s2 = (w + 1) * WIN + sj;
                    const int t2 = dir ? (T_ - 1 - s2) : s2;
                    xv[k] = (c < D0_) ? x[((size_t)(b0 + m) * T_ + t2) * D0_ + c] : 0.0f;
                }
            }

            unsigned short hb[4];
            #pragma unroll
            for (int r = 0; r < 4; ++r) {
                const float rg = sigf(aR0[r] + aR1[r]);
                const float zg = sigf(aZ0[r] + aZ1[r]);
                const float ng = tanhf_(fmaf(rg, aN0[r] + aN1[r], aX[r]));
                const float hn = fmaf(zg, hprev[r] - ng, ng);
                hprev[r] = hn;
                hb[r] = f2bu(hn);
            }
            uint2 wv2;
            wv2.x = (unsigned)hb[0] | ((unsigned)hb[1] << 16);
            wv2.y = (unsigned)hb[2] | ((unsigned)hb[3] << 16);
            *(uint2*)&hring[wb][woff] = wv2;

            if (si == 3 && w + 1 < NW) {
                #pragma unroll
                for (int k = 0; k < 4; ++k) {
                    const int i = tid + k * 512;
                    const int sj = i >> 9, rem = i & 511;
                    const int m = (rem >> 5) & 15, c = rem & 31;
                    xbuf[par ^ 1][sj][((c >> 3) * 16 + m) * 8 + (c & 7)] =
                        __float2bfloat16(xv[k]);
                }
            }
            flag_sync8(flags, wv, lane, (unsigned)(s + 1));
        }

        // flush h history: thread (dt, m, jo) reads uint4, coalesced global
        #pragma unroll
        for (int k = 0; k < 2; ++k) {
            const int c  = tid + k * 512;
            const int dt = c >> 8, m = (c >> 4) & 15, jo = c & 15;
            const int s  = w * WIN + dt;
            const int t  = dir ? (T_ - 1 - s) : s;
            const uint4 v = *(const uint4*)
                &hring[(s + 1) & (RING - 1)][(jo >> 2) * 512 + ((jo & 3) * 16 + m) * 8];
            *(uint4*)(l0h + ((size_t)(b0 + m) * T_ + t) * 256 + dir * H_ + jo * 8) = v;
        }
    }
}

// ---------------------------------------------------------------------------
// xg GEMM (both dirs, grid.z): D[j'][bt] = W_A . l0h_B + bias, emitted in
// scan C-layout: xgC[bg][t][g][jt][lane] as uint2 (4 consecutive j's, bf16).
// ---------------------------------------------------------------------------
__global__ __launch_bounds__(256, 2) void xg_gemm_mfma(
    const bf16* __restrict__ A,
    const float* __restrict__ w_f, const float* __restrict__ w_r,
    const float* __restrict__ bi_f, const float* __restrict__ bi_r,
    const float* __restrict__ bh_f, const float* __restrict__ bh_r,
    bf16* __restrict__ xg_f, bf16* __restrict__ xg_r)
{
    __shared__ short As[128 * 40];   // l0h rows (bt)
    __shared__ short Ws[128 * 40];   // W rows (j')
    __shared__ float Bias_s[128];

    const int dir  = blockIdx.z;
    const float* W   = dir ? w_r : w_f;
    const float* bi  = dir ? bi_r : bi_f;
    const float* bh  = dir ? bh_r : bh_f;
    bf16* xg         = dir ? xg_r : xg_f;

    const int tid  = threadIdx.x;
    const int lane = tid & 63;
    const int wv   = tid >> 6;
    const int col  = lane & 15;
    const int quad = lane >> 4;
    const int n0   = blockIdx.x * 128;        // bt base (single batch)
    const int g    = blockIdx.y;              // gate block
    const int m0   = g * 128;

    if (tid < 128) {
        const int n = m0 + tid;
        Bias_s[tid] = bi[n] + ((n < 2 * H_) ? bh[n] : 0.0f);
    }

    f32x4 acc[2][8];
    #pragma unroll
    for (int mt = 0; mt < 2; ++mt)
        #pragma unroll
        for (int nt = 0; nt < 8; ++nt) acc[mt][nt] = (f32x4){0.f, 0.f, 0.f, 0.f};

    for (int k0 = 0; k0 < 256; k0 += 32) {
        #pragma unroll
        for (int i = 0; i < 2; ++i) {
            const int c = tid + i * 256;
            const int row = c >> 2, q4 = c & 3;
            *(uint4*)&As[row * 40 + q4 * 8] =
                *(const uint4*)(A + (size_t)(n0 + row) * 256 + k0 + q4 * 8);
        }
        #pragma unroll
        for (int i = 0; i < 4; ++i) {
            const int c = tid + i * 256;
            const int row = c >> 3, q = c & 7;
            const float4 v = *(const float4*)(W + (size_t)(m0 + row) * 256 + k0 + q * 4);
            ushort4 u;
            u.x = f2bu(v.x); u.y = f2bu(v.y); u.z = f2bu(v.z); u.w = f2bu(v.w);
            *(ushort4*)&Ws[row * 40 + q * 4] = u;
        }
        __syncthreads();

        s16x8 wfr[2], hfr[8];
        #pragma unroll
        for (int mt = 0; mt < 2; ++mt)
            wfr[mt] = *(const s16x8*)&Ws[(wv * 32 + mt * 16 + col) * 40 + quad * 8];
        #pragma unroll
        for (int nt = 0; nt < 8; ++nt)
            hfr[nt] = *(const s16x8*)&As[(nt * 16 + col) * 40 + quad * 8];

        #pragma unroll
        for (int mt = 0; mt < 2; ++mt)
            #pragma unroll
            for (int nt = 0; nt < 8; ++nt)
                acc[mt][nt] = MFMA16(wfr[mt], hfr[nt], acc[mt][nt]);
        __syncthreads();
    }

    const int batch = n0 >> 11;
    const int bg = batch >> 4, cm = batch & 15;
    #pragma unroll
    for (int mt = 0; mt < 2; ++mt) {
        const int jt = wv * 2 + mt;
        float bv[4];
        #pragma unroll
        for (int r = 0; r < 4; ++r)
            bv[r] = Bias_s[wv * 32 + mt * 16 + quad * 4 + r];
        #pragma unroll
        for (int nt = 0; nt < 8; ++nt) {
            const int t = (n0 & 2047) + nt * 16 + col;
            uint2 o;
            o.x = (unsigned)f2bu(acc[mt][nt][0] + bv[0]) |
                  ((unsigned)f2bu(acc[mt][nt][1] + bv[1]) << 16);
            o.y = (unsigned)f2bu(acc[mt][nt][2] + bv[2]) |
                  ((unsigned)f2bu(acc[mt][nt][3] + bv[3]) << 16);
            const size_t idx = ((((size_t)bg * T_ + t) * 3 + g) * 8 + jt) * 64
                             + quad * 16 + cm;
            ((uint2*)xg)[idx] = o;
        }
    }
}

// ---------------------------------------------------------------------------
// Layer 1 scan: seeds from xgC (3 coalesced uint2/step, window-prefetched).
// ---------------------------------------------------------------------------
__global__ __launch_bounds__(512) void gru_l1_mfma(
    const bf16* __restrict__ xg_f, const bf16* __restrict__ xg_r,
    const float* __restrict__ whh_f, const float* __restrict__ bhh_f,
    const float* __restrict__ whh_r, const float* __restrict__ bhh_r,
    bf16* __restrict__ l1h, int fixed_dir)
{
    __shared__ __align__(16) bf16 hring[RING][2048];
    __shared__ volatile unsigned flags[8];

    const int bx   = blockIdx.x;
    const int dir  = (fixed_dir >= 0) ? fixed_dir : (bx >> 2);
    const int bg   = bx & 3;
    const int b0   = bg * 16;
    const int tid  = threadIdx.x;
    const int lane = tid & 63;
    const int wv   = tid >> 6;
    const int col  = lane & 15;
    const int quad = lane >> 4;

    const bf16*  XG  = dir ? xg_r : xg_f;
    const float* Whh = dir ? whh_r : whh_f;
    const float* Bhh = dir ? bhh_r : bhh_f;

    s16x8 wfr[3][4];
    #pragma unroll
    for (int g = 0; g < 3; ++g) {
        const float* wrow = Whh + (size_t)(g * H_ + wv * 16 + col) * H_;
        #pragma unroll
        for (int kt = 0; kt < 4; ++kt) {
            const float* p = wrow + kt * 32 + quad * 8;
            s16x8 f;
            #pragma unroll
            for (int i = 0; i < 8; ++i) f[i] = f2bs(p[i]);
            wfr[g][kt] = f;
        }
    }
    f32x4 sN;
    #pragma unroll
    for (int r = 0; r < 4; ++r)
        sN[r] = Bhh[2*H_ + wv * 16 + quad * 4 + r];
    const f32x4 z4 = (f32x4){0.f, 0.f, 0.f, 0.f};

    const int wkt  = wv >> 1;
    const int wl   = (((wv << 1) + (quad >> 1)) & 3) * 16 + col;
    const int woff = wkt * 512 + wl * 8 + (quad & 1) * 4;

    for (int i = tid; i < 2048; i += 512) hring[0][i] = __float2bfloat16(0.0f);
    if (tid < 8) flags[tid] = 0;

    const uint2* xgb = (const uint2*)XG + ((size_t)bg * T_) * 3 * 8 * 64;
    const int lidx = wv * 64 + lane;

    uint2 xcur[WIN][3], xnxt[WIN][3];
    #pragma unroll
    for (int si = 0; si < WIN; ++si) {
        const int t = dir ? (T_ - 1 - si) : si;
        #pragma unroll
        for (int g = 0; g < 3; ++g)
            xcur[si][g] = xgb[((size_t)t * 3 + g) * 512 + lidx];
    }
    __syncthreads();

    float hprev[4] = {0.f, 0.f, 0.f, 0.f};

    for (int w = 0; w < NW; ++w) {
        #pragma unroll
        for (int si = 0; si < WIN; ++si) {
            const int s  = w * WIN + si;
            const int rb = s & (RING - 1);
            const int wb = (s + 1) & (RING - 1);

            s16x8 hfr[4];
            #pragma unroll
            for (int kt = 0; kt < 4; ++kt)
                hfr[kt] = *(const s16x8*)&hring[rb][kt * 512 + lane * 8];

            // unpack seeds while ds_reads are in flight
            const uint2 xr2 = xcur[si][0], xz2 = xcur[si][1], xn2 = xcur[si][2];
            const f32x4 seedR = (f32x4){
                __uint_as_float(xr2.x << 16), __uint_as_float(xr2.x & 0xffff0000u),
                __uint_as_float(xr2.y << 16), __uint_as_float(xr2.y & 0xffff0000u)};
            const f32x4 seedZ = (f32x4){
                __uint_as_float(xz2.x << 16), __uint_as_float(xz2.x & 0xffff0000u),
                __uint_as_float(xz2.y << 16), __uint_as_float(xz2.y & 0xffff0000u)};
            const float xnf[4] = {
                __uint_as_float(xn2.x << 16), __uint_as_float(xn2.x & 0xffff0000u),
                __uint_as_float(xn2.y << 16), __uint_as_float(xn2.y & 0xffff0000u)};

            f32x4 aR0 = MFMA16(wfr[0][0], hfr[0], seedR);
            f32x4 aZ0 = MFMA16(wfr[1][0], hfr[0], seedZ);
            f32x4 aN0 = MFMA16(wfr[2][0], hfr[0], sN);
            f32x4 aR1 = MFMA16(wfr[0][2], hfr[2], z4);
            f32x4 aZ1 = MFMA16(wfr[1][2], hfr[2], z4);
            f32x4 aN1 = MFMA16(wfr[2][2], hfr[2], z4);
            aR0 = MFMA16(wfr[0][1], hfr[1], aR0);
            aZ0 = MFMA16(wfr[1][1], hfr[1], aZ0);
            aN0 = MFMA16(wfr[2][1], hfr[1], aN0);
            aR1 = MFMA16(wfr[0][3], hfr[3], aR1);
            aZ1 = MFMA16(wfr[1][3], hfr[3], aZ1);
            aN1 = MFMA16(wfr[2][3], hfr[3], aN1);

            if (si == 0 && w + 1 < NW) {
                #pragma unroll
                for (int sj = 0; sj < WIN; ++sj) {
                    const int s2 = (w + 1) * WIN + sj;
                    const int t2 = dir ? (T_ - 1 - s2) : s2;
                    #pragma unroll
                    for (int g = 0; g < 3; ++g)
                        xnxt[sj][g] = xgb[((size_t)t2 * 3 + g) * 512 + lidx];
                }
            }

            unsigned short hb[4];
            #pragma unroll
            for (int r = 0; r < 4; ++r) {
                const float rg = sigf(aR0[r] + aR1[r]);
                const float zg = sigf(aZ0[r] + aZ1[r]);
                const float ng = tanhf_(fmaf(rg, aN0[r] + aN1[r], xnf[r]));
                const float hn = fmaf(zg, hprev[r] - ng, ng);
                hprev[r] = hn;
                hb[r] = f2bu(hn);
            }
            uint2 wv2;
            wv2.x = (unsigned)hb[0] | ((unsigned)hb[1] << 16);
            wv2.y = (unsigned)hb[2] | ((unsigned)hb[3] << 16);
            *(uint2*)&hring[wb][woff] = wv2;

            flag_sync8(flags, wv, lane, (unsigned)(s + 1));
        }

        #pragma unroll
        for (int k = 0; k < 2; ++k) {
            const int c  = tid + k * 512;
            const int dt = c >> 8, m = (c >> 4) & 15, jo = c & 15;
            const int s  = w * WIN + dt;
            const int t  = dir ? (T_ - 1 - s) : s;
            const uint4 v = *(const uint4*)
                &hring[(s + 1) & (RING - 1)][(jo >> 2) * 512 + ((jo & 3) * 16 + m) * 8];
            *(uint4*)(l1h + ((size_t)(b0 + m) * T_ + t) * 256 + dir * H_ + jo * 8) = v;
        }
        #pragma unroll
        for (int si = 0; si < WIN; ++si) {
            xcur[si][0] = xnxt[si][0];
            xcur[si][1] = xnxt[si][1];
            xcur[si][2] = xnxt[si][2];
        }
    }
}

// ---------------------------------------------------------------------------
// FC epilogue: out[bt][c] = fc_b[c] + fc_w[c][:] . l1h[bt][:]
// ---------------------------------------------------------------------------
__global__ __launch_bounds__(256, 2) void fc_kernel(
    const bf16* __restrict__ h, const float* __restrict__ fcw,
    const float* __restrict__ fcb, float* __restrict__ out)
{
    __shared__ float w0[256], w1[256];
    const int tid = threadIdx.x;
    w0[tid] = fcw[tid];
    w1[tid] = fcw[256 + tid];
    __syncthreads();

    const size_t bt = (size_t)blockIdx.x * 256 + tid;
    const bf16* hp = h + bt * 256;
    float s0 = fcb[0], s1 = fcb[1];
    #pragma unroll 4
    for (int k8 = 0; k8 < 32; ++k8) {
        const uint4 u = *(const uint4*)(hp + k8 * 8);
        const unsigned uu[4] = {u.x, u.y, u.z, u.w};
        #pragma unroll
        for (int p = 0; p < 4; ++p) {
            const float v0 = __uint_as_float(uu[p] << 16);
            const float v1 = __uint_as_float(uu[p] & 0xffff0000u);
            const int k = k8 * 8 + p * 2;
            s0 = fmaf(w0[k], v0, s0);     s1 = fmaf(w1[k], v0, s1);
            s0 = fmaf(w0[k + 1], v1, s0); s1 = fmaf(w1[k + 1], v1, s1);
        }
    }
    out[bt * 2]     = s0;
    out[bt * 2 + 1] = s1;
}

extern "C" void kernel_launch(void* const* d_in, const int* in_sizes, int n_in,
                              void* d_out, int out_size, void* d_ws, size_t ws_size,
                              hipStream_t stream)
{
    if (n_in < 19) return;
    const float* x     = (const float*)d_in[0];
    const float* wih0  = (const float*)d_in[1];
    const float* whh0  = (const float*)d_in[2];
    const float* bih0  = (const float*)d_in[3];
    const float* bhh0  = (const float*)d_in[4];
    const float* wih0r = (const float*)d_in[5];
    const float* whh0r = (const float*)d_in[6];
    const float* bih0r = (const float*)d_in[7];
    const float* bhh0r = (const float*)d_in[8];
    const float* wih1  = (const float*)d_in[9];
    const float* whh1  = (const float*)d_in[10];
    const float* bih1  = (const float*)d_in[11];
    const float* bhh1  = (const float*)d_in[12];
    const float* wih1r = (const float*)d_in[13];
    const float* whh1r = (const float*)d_in[14];
    const float* bih1r = (const float*)d_in[15];
    const float* bhh1r = (const float*)d_in[16];
    const float* fcw   = (const float*)d_in[17];
    const float* fcb   = (const float*)d_in[18];
    float* out = (float*)d_out;

    const size_t nBT  = (size_t)B_ * T_;
    const size_t hh_b = nBT * 2 * H_ * sizeof(bf16);     // 64 MiB
    const size_t xg_b = nBT * G_ * sizeof(bf16);         // 96 MiB per dir
    const size_t xg_el = nBT * G_;

    if (ws_size >= hh_b + 2 * xg_b) {                    // 256 MiB path
        bf16* l0h = (bf16*)d_ws;
        bf16* xgf = (bf16*)((char*)d_ws + hh_b);
        bf16* xgr = xgf + xg_el;

        gru_l0_mfma<<<dim3(8), dim3(512), 0, stream>>>(
            x, wih0, whh0, bih0, bhh0, wih0r, whh0r, bih0r, bhh0r, l0h);
        xg_gemm_mfma<<<dim3(1024, 3, 2), dim3(256), 0, stream>>>(
            l0h, wih1, wih1r, bih1, bih1r, bhh1, bhh1r, xgf, xgr);
        gru_l1_mfma<<<dim3(8), dim3(512), 0, stream>>>(
            xgf, xgr, whh1, bhh1, whh1r, bhh1r, l0h, -1);   // l1h aliases l0h
        fc_kernel<<<dim3((int)(nBT / 256)), dim3(256), 0, stream>>>(l0h, fcw, fcb, out);
    } else if (ws_size >= 2 * hh_b + xg_b) {             // 224 MiB sequential
        bf16* l0h = (bf16*)d_ws;
        bf16* xg  = (bf16*)((char*)d_ws + hh_b);
        bf16* l1h = (bf16*)((char*)d_ws + hh_b + xg_b);

        gru_l0_mfma<<<dim3(8), dim3(512), 0, stream>>>(
            x, wih0, whh0, bih0, bhh0, wih0r, whh0r, bih0r, bhh0r, l0h);
        xg_gemm_mfma<<<dim3(1024, 3, 1), dim3(256), 0, stream>>>(
            l0h, wih1, wih1, bih1, bih1, bhh1, bhh1, xg, xg);
        gru_l1_mfma<<<dim3(4), dim3(512), 0, stream>>>(
            xg, xg, whh1, bhh1, whh1r, bhh1r, l1h, 0);
        xg_gemm_mfma<<<dim3(1024, 3, 1), dim3(256), 0, stream>>>(
            l0h, wih1r, wih1r, bih1r, bih1r, bhh1r, bhh1r, xg, xg);
        gru_l1_mfma<<<dim3(4), dim3(512), 0, stream>>>(
            xg, xg, whh1, bhh1, whh1r, bhh1r, l1h, 1);
        fc_kernel<<<dim3((int)(nBT / 256)), dim3(256), 0, stream>>>(l1h, fcw, fcb, out);
    }
}

// Round 17
// 3719.152 us; speedup vs baseline: 1.1910x; 1.1254x over previous
//
#include <hip/hip_runtime.h>
#include <hip/hip_bf16.h>

#define B_   64
#define T_   2048
#define H_   128
#define G_   384      // 3*H
#define D0_  18
#define WIN  4
#define RING 8
#define NW   (T_ / WIN)   // 512

typedef __hip_bfloat16 bf16;
typedef __attribute__((ext_vector_type(4))) float f32x4;
typedef __attribute__((ext_vector_type(8))) short s16x8;

#define LOG2E 1.4426950408889634f
__device__ __forceinline__ float sigf(float x) {
    return __builtin_amdgcn_rcpf(1.0f + __builtin_amdgcn_exp2f(-LOG2E * x));
}
__device__ __forceinline__ float tanhf_(float x) {
    return 1.0f - 2.0f * __builtin_amdgcn_rcpf(1.0f + __builtin_amdgcn_exp2f((2.0f * LOG2E) * x));
}
__device__ __forceinline__ short f2bs(float v) {
    bf16 b = __float2bfloat16(v);
    return *reinterpret_cast<short*>(&b);
}
__device__ __forceinline__ unsigned short f2bu(float v) {
    bf16 b = __float2bfloat16(v);
    return *reinterpret_cast<unsigned short*>(&b);
}
#define MFMA16(A, B, C) __builtin_amdgcn_mfma_f32_16x16x32_bf16((A), (B), (C), 0, 0, 0)

// Fence-free WG wave sync (validated R13: DS ops from one wave execute in
// order, so the counter bump issued after h'-writes implies their visibility).
__device__ __forceinline__ void wave_sync(unsigned* cnt, int lane, unsigned tgt) {
    __asm__ volatile("" ::: "memory");
    if (lane == 0)
        __hip_atomic_fetch_add(cnt, 1u, __ATOMIC_RELAXED, __HIP_MEMORY_SCOPE_WORKGROUP);
    while (__hip_atomic_load(cnt, __ATOMIC_RELAXED, __HIP_MEMORY_SCOPE_WORKGROUP) < tgt) {}
    __asm__ volatile("" ::: "memory");
}

// h ring slot: B-frag order. flat short idx = kt*512 + l*8 + i holds
// h[k = kt*32 + (l>>4)*8 + i][batch = l&15]. Reads: ds_read_b128 at lane*16B
// (conflict-free canonical). Writes: one ds_write_b64 per lane (4-way).

// ---------------------------------------------------------------------------
// Layer 0 scan: gates D[j][m] = Whh_A . h_B (+ Wih_A . x_B). 8 WGs x 512 thr.
// ---------------------------------------------------------------------------
__global__ __launch_bounds__(512) void gru_l0_mfma(
    const float* __restrict__ x,
    const float* __restrict__ wih_f, const float* __restrict__ whh_f,
    const float* __restrict__ bih_f, const float* __restrict__ bhh_f,
    const float* __restrict__ wih_r, const float* __restrict__ whh_r,
    const float* __restrict__ bih_r, const float* __restrict__ bhh_r,
    bf16* __restrict__ l0h)
{
    __shared__ __align__(16) bf16 hring[RING][2048];
    __shared__ __align__(16) bf16 xbuf[2][WIN][512];   // B-frag order, k<32 pad
    __shared__ unsigned syncnt;

    const int bx   = blockIdx.x;
    const int dir  = bx >> 2;
    const int bg   = bx & 3;
    const int b0   = bg * 16;
    const int tid  = threadIdx.x;
    const int lane = tid & 63;
    const int wv   = tid >> 6;       // = jt (j-tile)
    const int col  = lane & 15;
    const int quad = lane >> 4;

    const float* Wih = dir ? wih_r : wih_f;
    const float* Whh = dir ? whh_r : whh_f;
    const float* Bih = dir ? bih_r : bih_f;
    const float* Bhh = dir ? bhh_r : bhh_f;

    // A-frags: lane holds W[row = tile + col][k = kt*32 + quad*8 + i]
    s16x8 wfr[3][4], wxf[3];
    #pragma unroll
    for (int g = 0; g < 3; ++g) {
        const float* wrow = Whh + (size_t)(g * H_ + wv * 16 + col) * H_;
        #pragma unroll
        for (int kt = 0; kt < 4; ++kt) {
            const float* p = wrow + kt * 32 + quad * 8;
            s16x8 f;
            #pragma unroll
            for (int i = 0; i < 8; ++i) f[i] = f2bs(p[i]);
            wfr[g][kt] = f;
        }
        const float* xrow = Wih + (size_t)(g * H_ + wv * 16 + col) * D0_;
        s16x8 fx;
        #pragma unroll
        for (int i = 0; i < 8; ++i) {
            const int k = quad * 8 + i;
            fx[i] = (k < D0_) ? f2bs(xrow[k]) : (short)0;
        }
        wxf[g] = fx;
    }
    // per-r seeds: j = wv*16 + quad*4 + r
    f32x4 sR, sZ, sX, sN;
    #pragma unroll
    for (int r = 0; r < 4; ++r) {
        const int j = wv * 16 + quad * 4 + r;
        sR[r] = Bih[j]        + Bhh[j];
        sZ[r] = Bih[H_ + j]   + Bhh[H_ + j];
        sX[r] = Bih[2*H_ + j];
        sN[r] = Bhh[2*H_ + j];
    }
    const f32x4 z4 = (f32x4){0.f, 0.f, 0.f, 0.f};

    // h' write slot (B-frag position for j = wv*16+quad*4+r, m = col)
    const int wkt   = wv >> 1;
    const int wl    = (((wv << 1) + (quad >> 1)) & 3) * 16 + col;
    const int woff  = wkt * 512 + wl * 8 + (quad & 1) * 4;   // shorts

    for (int i = tid; i < 2048; i += 512) hring[0][i] = __float2bfloat16(0.0f);
    if (tid == 0) syncnt = 0;
    // stage x window 0 (B-frag order)
    #pragma unroll
    for (int k = 0; k < 4; ++k) {
        const int i = tid + k * 512;
        const int si = i >> 9, rem = i & 511;
        const int m = (rem >> 5) & 15, c = rem & 31;
        const int t = dir ? (T_ - 1 - si) : si;
        const float v = (c < D0_) ? x[((size_t)(b0 + m) * T_ + t) * D0_ + c] : 0.0f;
        xbuf[0][si][((c >> 3) * 16 + m) * 8 + (c & 7)] = __float2bfloat16(v);
    }
    __syncthreads();

    float hprev[4] = {0.f, 0.f, 0.f, 0.f};
    float xv[4];

    for (int w = 0; w < NW; ++w) {
        const int par = w & 1;
        s16x8 axf[WIN];
        #pragma unroll
        for (int si = 0; si < WIN; ++si)
            axf[si] = *(const s16x8*)&xbuf[par][si][lane * 8];

        #pragma unroll
        for (int si = 0; si < WIN; ++si) {
            const int s  = w * WIN + si;
            const int rb = s & (RING - 1);
            const int wb = (s + 1) & (RING - 1);

            // B-frag h reads: contiguous lane*16B per kt block (conflict-free)
            s16x8 hfr[4];
            #pragma unroll
            for (int kt = 0; kt < 4; ++kt)
                hfr[kt] = *(const s16x8*)&hring[rb][kt * 512 + lane * 8];

            // x-MFMAs fill the ds_read latency
            f32x4 aR1 = MFMA16(wxf[0], axf[si], z4);
            f32x4 aZ1 = MFMA16(wxf[1], axf[si], z4);
            f32x4 aX  = MFMA16(wxf[2], axf[si], sX);

            f32x4 aR0 = MFMA16(wfr[0][0], hfr[0], sR);
            f32x4 aZ0 = MFMA16(wfr[1][0], hfr[0], sZ);
            f32x4 aN0 = MFMA16(wfr[2][0], hfr[0], sN);
            aR1 = MFMA16(wfr[0][2], hfr[2], aR1);
            aZ1 = MFMA16(wfr[1][2], hfr[2], aZ1);
            f32x4 aN1 = MFMA16(wfr[2][2], hfr[2], z4);
            aR0 = MFMA16(wfr[0][1], hfr[1], aR0);
            aZ0 = MFMA16(wfr[1][1], hfr[1], aZ0);
            aN0 = MFMA16(wfr[2][1], hfr[1], aN0);
            aR1 = MFMA16(wfr[0][3], hfr[3], aR1);
            aZ1 = MFMA16(wfr[1][3], hfr[3], aZ1);
            aN1 = MFMA16(wfr[2][3], hfr[3], aN1);

            // prefetch next window's x in the MFMA shadow
            if (si == 0 && w + 1 < NW) {
                #pragma unroll
                for (int k = 0; k < 4; ++k) {
                    const int i = tid + k * 512;
                    const int sj = i >> 9, rem = i & 511;
                    const int m = (rem >> 5) & 15, c = rem & 31;
                    const int s2 = (w + 1) * WIN + sj;
                    const int t2 = dir ? (T_ - 1 - s2) : s2;
                    xv[k] = (c < D0_) ? x[((size_t)(b0 + m) * T_ + t2) * D0_ + c] : 0.0f;
                }
            }

            unsigned short hb[4];
            #pragma unroll
            for (int r = 0; r < 4; ++r) {
                const float rg = sigf(aR0[r] + aR1[r]);
                const float zg = sigf(aZ0[r] + aZ1[r]);
                const float ng = tanhf_(fmaf(rg, aN0[r] + aN1[r], aX[r]));
                const float hn = fmaf(zg, hprev[r] - ng, ng);
                hprev[r] = hn;
                hb[r] = f2bu(hn);
            }
            // single b64 store of 4 consecutive bf16
            uint2 wv2;
            wv2.x = (unsigned)hb[0] | ((unsigned)hb[1] << 16);
            wv2.y = (unsigned)hb[2] | ((unsigned)hb[3] << 16);
            *(uint2*)&hring[wb][woff] = wv2;

            if (si == 3 && w + 1 < NW) {
                #pragma unroll
                for (int k = 0; k < 4; ++k) {
                    const int i = tid + k * 512;
                    const int sj = i >> 9, rem = i & 511;
                    const int m = (rem >> 5) & 15, c = rem & 31;
                    xbuf[par ^ 1][sj][((c >> 3) * 16 + m) * 8 + (c & 7)] =
                        __float2bfloat16(xv[k]);
                }
            }
            wave_sync(&syncnt, lane, (unsigned)(s + 1) * 8u);
        }

        // flush h history: thread (dt, m, jo) reads uint4, coalesced global
        #pragma unroll
        for (int k = 0; k < 2; ++k) {
            const int c  = tid + k * 512;
            const int dt = c >> 8, m = (c >> 4) & 15, jo = c & 15;
            const int s  = w * WIN + dt;
            const int t  = dir ? (T_ - 1 - s) : s;
            const uint4 v = *(const uint4*)
                &hring[(s + 1) & (RING - 1)][(jo >> 2) * 512 + ((jo & 3) * 16 + m) * 8];
            *(uint4*)(l0h + ((size_t)(b0 + m) * T_ + t) * 256 + dir * H_ + jo * 8) = v;
        }
    }
}

// ---------------------------------------------------------------------------
// xg GEMM (both dirs, grid.z): D[j'][bt] = W_A . l0h_B + bias, emitted in
// scan C-layout: xgC[bg][t][g][jt][lane] as uint2 (4 consecutive j's, bf16).
// ---------------------------------------------------------------------------
__global__ __launch_bounds__(256, 2) void xg_gemm_mfma(
    const bf16* __restrict__ A,
    const float* __restrict__ w_f, const float* __restrict__ w_r,
    const float* __restrict__ bi_f, const float* __restrict__ bi_r,
    const float* __restrict__ bh_f, const float* __restrict__ bh_r,
    bf16* __restrict__ xg_f, bf16* __restrict__ xg_r)
{
    __shared__ short As[128 * 40];   // l0h rows (bt)
    __shared__ short Ws[128 * 40];   // W rows (j')
    __shared__ float Bias_s[128];

    const int dir  = blockIdx.z;
    const float* W   = dir ? w_r : w_f;
    const float* bi  = dir ? bi_r : bi_f;
    const float* bh  = dir ? bh_r : bh_f;
    bf16* xg         = dir ? xg_r : xg_f;

    const int tid  = threadIdx.x;
    const int lane = tid & 63;
    const int wv   = tid >> 6;
    const int col  = lane & 15;
    const int quad = lane >> 4;
    const int n0   = blockIdx.x * 128;        // bt base (single batch)
    const int g    = blockIdx.y;              // gate block
    const int m0   = g * 128;

    if (tid < 128) {
        const int n = m0 + tid;
        Bias_s[tid] = bi[n] + ((n < 2 * H_) ? bh[n] : 0.0f);
    }

    f32x4 acc[2][8];
    #pragma unroll
    for (int mt = 0; mt < 2; ++mt)
        #pragma unroll
        for (int nt = 0; nt < 8; ++nt) acc[mt][nt] = (f32x4){0.f, 0.f, 0.f, 0.f};

    for (int k0 = 0; k0 < 256; k0 += 32) {
        #pragma unroll
        for (int i = 0; i < 2; ++i) {
            const int c = tid + i * 256;
            const int row = c >> 2, q4 = c & 3;
            *(uint4*)&As[row * 40 + q4 * 8] =
                *(const uint4*)(A + (size_t)(n0 + row) * 256 + k0 + q4 * 8);
        }
        #pragma unroll
        for (int i = 0; i < 4; ++i) {
            const int c = tid + i * 256;
            const int row = c >> 3, q = c & 7;
            const float4 v = *(const float4*)(W + (size_t)(m0 + row) * 256 + k0 + q * 4);
            ushort4 u;
            u.x = f2bu(v.x); u.y = f2bu(v.y); u.z = f2bu(v.z); u.w = f2bu(v.w);
            *(ushort4*)&Ws[row * 40 + q * 4] = u;
        }
        __syncthreads();

        s16x8 wfr[2], hfr[8];
        #pragma unroll
        for (int mt = 0; mt < 2; ++mt)
            wfr[mt] = *(const s16x8*)&Ws[(wv * 32 + mt * 16 + col) * 40 + quad * 8];
        #pragma unroll
        for (int nt = 0; nt < 8; ++nt)
            hfr[nt] = *(const s16x8*)&As[(nt * 16 + col) * 40 + quad * 8];

        #pragma unroll
        for (int mt = 0; mt < 2; ++mt)
            #pragma unroll
            for (int nt = 0; nt < 8; ++nt)
                acc[mt][nt] = MFMA16(wfr[mt], hfr[nt], acc[mt][nt]);
        __syncthreads();
    }

    const int batch = n0 >> 11;
    const int bg = batch >> 4, cm = batch & 15;
    #pragma unroll
    for (int mt = 0; mt < 2; ++mt) {
        const int jt = wv * 2 + mt;
        float bv[4];
        #pragma unroll
        for (int r = 0; r < 4; ++r)
            bv[r] = Bias_s[wv * 32 + mt * 16 + quad * 4 + r];
        #pragma unroll
        for (int nt = 0; nt < 8; ++nt) {
            const int t = (n0 & 2047) + nt * 16 + col;
            uint2 o;
            o.x = (unsigned)f2bu(acc[mt][nt][0] + bv[0]) |
                  ((unsigned)f2bu(acc[mt][nt][1] + bv[1]) << 16);
            o.y = (unsigned)f2bu(acc[mt][nt][2] + bv[2]) |
                  ((unsigned)f2bu(acc[mt][nt][3] + bv[3]) << 16);
            const size_t idx = ((((size_t)bg * T_ + t) * 3 + g) * 8 + jt) * 64
                             + quad * 16 + cm;
            ((uint2*)xg)[idx] = o;
        }
    }
}

// ---------------------------------------------------------------------------
// Layer 1 scan: seeds from xgC (3 coalesced uint2/step, window-prefetched).
// ---------------------------------------------------------------------------
__global__ __launch_bounds__(512) void gru_l1_mfma(
    const bf16* __restrict__ xg_f, const bf16* __restrict__ xg_r,
    const float* __restrict__ whh_f, const float* __restrict__ bhh_f,
    const float* __restrict__ whh_r, const float* __restrict__ bhh_r,
    bf16* __restrict__ l1h, int fixed_dir)
{
    __shared__ __align__(16) bf16 hring[RING][2048];
    __shared__ unsigned syncnt;

    const int bx   = blockIdx.x;
    const int dir  = (fixed_dir >= 0) ? fixed_dir : (bx >> 2);
    const int bg   = bx & 3;
    const int b0   = bg * 16;
    const int tid  = threadIdx.x;
    const int lane = tid & 63;
    const int wv   = tid >> 6;
    const int col  = lane & 15;
    const int quad = lane >> 4;

    const bf16*  XG  = dir ? xg_r : xg_f;
    const float* Whh = dir ? whh_r : whh_f;
    const float* Bhh = dir ? bhh_r : bhh_f;

    s16x8 wfr[3][4];
    #pragma unroll
    for (int g = 0; g < 3; ++g) {
        const float* wrow = Whh + (size_t)(g * H_ + wv * 16 + col) * H_;
        #pragma unroll
        for (int kt = 0; kt < 4; ++kt) {
            const float* p = wrow + kt * 32 + quad * 8;
            s16x8 f;
            #pragma unroll
            for (int i = 0; i < 8; ++i) f[i] = f2bs(p[i]);
            wfr[g][kt] = f;
        }
    }
    f32x4 sN;
    #pragma unroll
    for (int r = 0; r < 4; ++r)
        sN[r] = Bhh[2*H_ + wv * 16 + quad * 4 + r];
    const f32x4 z4 = (f32x4){0.f, 0.f, 0.f, 0.f};

    const int wkt  = wv >> 1;
    const int wl   = (((wv << 1) + (quad >> 1)) & 3) * 16 + col;
    const int woff = wkt * 512 + wl * 8 + (quad & 1) * 4;

    for (int i = tid; i < 2048; i += 512) hring[0][i] = __float2bfloat16(0.0f);
    if (tid == 0) syncnt = 0;

    const uint2* xgb = (const uint2*)XG + ((size_t)bg * T_) * 3 * 8 * 64;
    const int lidx = wv * 64 + lane;

    uint2 xcur[WIN][3], xnxt[WIN][3];
    #pragma unroll
    for (int si = 0; si < WIN; ++si) {
        const int t = dir ? (T_ - 1 - si) : si;
        #pragma unroll
        for (int g = 0; g < 3; ++g)
            xcur[si][g] = xgb[((size_t)t * 3 + g) * 512 + lidx];
    }
    __syncthreads();

    float hprev[4] = {0.f, 0.f, 0.f, 0.f};

    for (int w = 0; w < NW; ++w) {
        #pragma unroll
        for (int si = 0; si < WIN; ++si) {
            const int s  = w * WIN + si;
            const int rb = s & (RING - 1);
            const int wb = (s + 1) & (RING - 1);

            s16x8 hfr[4];
            #pragma unroll
            for (int kt = 0; kt < 4; ++kt)
                hfr[kt] = *(const s16x8*)&hring[rb][kt * 512 + lane * 8];

            // unpack seeds while ds_reads are in flight
            const uint2 xr2 = xcur[si][0], xz2 = xcur[si][1], xn2 = xcur[si][2];
            const f32x4 seedR = (f32x4){
                __uint_as_float(xr2.x << 16), __uint_as_float(xr2.x & 0xffff0000u),
                __uint_as_float(xr2.y << 16), __uint_as_float(xr2.y & 0xffff0000u)};
            const f32x4 seedZ = (f32x4){
                __uint_as_float(xz2.x << 16), __uint_as_float(xz2.x & 0xffff0000u),
                __uint_as_float(xz2.y << 16), __uint_as_float(xz2.y & 0xffff0000u)};
            const float xnf[4] = {
                __uint_as_float(xn2.x << 16), __uint_as_float(xn2.x & 0xffff0000u),
                __uint_as_float(xn2.y << 16), __uint_as_float(xn2.y & 0xffff0000u)};

            f32x4 aR0 = MFMA16(wfr[0][0], hfr[0], seedR);
            f32x4 aZ0 = MFMA16(wfr[1][0], hfr[0], seedZ);
            f32x4 aN0 = MFMA16(wfr[2][0], hfr[0], sN);
            f32x4 aR1 = MFMA16(wfr[0][2], hfr[2], z4);
            f32x4 aZ1 = MFMA16(wfr[1][2], hfr[2], z4);
            f32x4 aN1 = MFMA16(wfr[2][2], hfr[2], z4);
            aR0 = MFMA16(wfr[0][1], hfr[1], aR0);
            aZ0 = MFMA16(wfr[1][1], hfr[1], aZ0);
            aN0 = MFMA16(wfr[2][1], hfr[1], aN0);
            aR1 = MFMA16(wfr[0][3], hfr[3], aR1);
            aZ1 = MFMA16(wfr[1][3], hfr[3], aZ1);
            aN1 = MFMA16(wfr[2][3], hfr[3], aN1);

            if (si == 0 && w + 1 < NW) {
                #pragma unroll
                for (int sj = 0; sj < WIN; ++sj) {
                    const int s2 = (w + 1) * WIN + sj;
                    const int t2 = dir ? (T_ - 1 - s2) : s2;
                    #pragma unroll
                    for (int g = 0; g < 3; ++g)
                        xnxt[sj][g] = xgb[((size_t)t2 * 3 + g) * 512 + lidx];
                }
            }

            unsigned short hb[4];
            #pragma unroll
            for (int r = 0; r < 4; ++r) {
                const float rg = sigf(aR0[r] + aR1[r]);
                const float zg = sigf(aZ0[r] + aZ1[r]);
                const float ng = tanhf_(fmaf(rg, aN0[r] + aN1[r], xnf[r]));
                const float hn = fmaf(zg, hprev[r] - ng, ng);
                hprev[r] = hn;
                hb[r] = f2bu(hn);
            }
            uint2 wv2;
            wv2.x = (unsigned)hb[0] | ((unsigned)hb[1] << 16);
            wv2.y = (unsigned)hb[2] | ((unsigned)hb[3] << 16);
            *(uint2*)&hring[wb][woff] = wv2;

            wave_sync(&syncnt, lane, (unsigned)(s + 1) * 8u);
        }

        #pragma unroll
        for (int k = 0; k < 2; ++k) {
            const int c  = tid + k * 512;
            const int dt = c >> 8, m = (c >> 4) & 15, jo = c & 15;
            const int s  = w * WIN + dt;
            const int t  = dir ? (T_ - 1 - s) : s;
            const uint4 v = *(const uint4*)
                &hring[(s + 1) & (RING - 1)][(jo >> 2) * 512 + ((jo & 3) * 16 + m) * 8];
            *(uint4*)(l1h + ((size_t)(b0 + m) * T_ + t) * 256 + dir * H_ + jo * 8) = v;
        }
        #pragma unroll
        for (int si = 0; si < WIN; ++si) {
            xcur[si][0] = xnxt[si][0];
            xcur[si][1] = xnxt[si][1];
            xcur[si][2] = xnxt[si][2];
        }
    }
}

// ---------------------------------------------------------------------------
// FC epilogue: out[bt][c] = fc_b[c] + fc_w[c][:] . l1h[bt][:]
// ---------------------------------------------------------------------------
__global__ __launch_bounds__(256, 2) void fc_kernel(
    const bf16* __restrict__ h, const float* __restrict__ fcw,
    const float* __restrict__ fcb, float* __restrict__ out)
{
    __shared__ float w0[256], w1[256];
    const int tid = threadIdx.x;
    w0[tid] = fcw[tid];
    w1[tid] = fcw[256 + tid];
    __syncthreads();

    const size_t bt = (size_t)blockIdx.x * 256 + tid;
    const bf16* hp = h + bt * 256;
    float s0 = fcb[0], s1 = fcb[1];
    #pragma unroll 4
    for (int k8 = 0; k8 < 32; ++k8) {
        const uint4 u = *(const uint4*)(hp + k8 * 8);
        const unsigned uu[4] = {u.x, u.y, u.z, u.w};
        #pragma unroll
        for (int p = 0; p < 4; ++p) {
            const float v0 = __uint_as_float(uu[p] << 16);
            const float v1 = __uint_as_float(uu[p] & 0xffff0000u);
            const int k = k8 * 8 + p * 2;
            s0 = fmaf(w0[k], v0, s0);     s1 = fmaf(w1[k], v0, s1);
            s0 = fmaf(w0[k + 1], v1, s0); s1 = fmaf(w1[k + 1], v1, s1);
        }
    }
    out[bt * 2]     = s0;
    out[bt * 2 + 1] = s1;
}

extern "C" void kernel_launch(void* const* d_in, const int* in_sizes, int n_in,
                              void* d_out, int out_size, void* d_ws, size_t ws_size,
                              hipStream_t stream)
{
    if (n_in < 19) return;
    const float* x     = (const float*)d_in[0];
    const float* wih0  = (const float*)d_in[1];
    const float* whh0  = (const float*)d_in[2];
    const float* bih0  = (const float*)d_in[3];
    const float* bhh0  = (const float*)d_in[4];
    const float* wih0r = (const float*)d_in[5];
    const float* whh0r = (const float*)d_in[6];
    const float* bih0r = (const float*)d_in[7];
    const float* bhh0r = (const float*)d_in[8];
    const float* wih1  = (const float*)d_in[9];
    const float* whh1  = (const float*)d_in[10];
    const float* bih1  = (const float*)d_in[11];
    const float* bhh1  = (const float*)d_in[12];
    const float* wih1r = (const float*)d_in[13];
    const float* whh1r = (const float*)d_in[14];
    const float* bih1r = (const float*)d_in[15];
    const float* bhh1r = (const float*)d_in[16];
    const float* fcw   = (const float*)d_in[17];
    const float* fcb   = (const float*)d_in[18];
    float* out = (float*)d_out;

    const size_t nBT  = (size_t)B_ * T_;
    const size_t hh_b = nBT * 2 * H_ * sizeof(bf16);     // 64 MiB
    const size_t xg_b = nBT * G_ * sizeof(bf16);         // 96 MiB per dir
    const size_t xg_el = nBT * G_;

    if (ws_size >= hh_b + 2 * xg_b) {                    // 256 MiB path
        bf16* l0h = (bf16*)d_ws;
        bf16* xgf = (bf16*)((char*)d_ws + hh_b);
        bf16* xgr = xgf + xg_el;

        gru_l0_mfma<<<dim3(8), dim3(512), 0, stream>>>(
            x, wih0, whh0, bih0, bhh0, wih0r, whh0r, bih0r, bhh0r, l0h);
        xg_gemm_mfma<<<dim3(1024, 3, 2), dim3(256), 0, stream>>>(
            l0h, wih1, wih1r, bih1, bih1r, bhh1, bhh1r, xgf, xgr);
        gru_l1_mfma<<<dim3(8), dim3(512), 0, stream>>>(
            xgf, xgr, whh1, bhh1, whh1r, bhh1r, l0h, -1);   // l1h aliases l0h
        fc_kernel<<<dim3((int)(nBT / 256)), dim3(256), 0, stream>>>(l0h, fcw, fcb, out);
    } else if (ws_size >= 2 * hh_b + xg_b) {             // 224 MiB sequential
        bf16* l0h = (bf16*)d_ws;
        bf16* xg  = (bf16*)((char*)d_ws + hh_b);
        bf16* l1h = (bf16*)((char*)d_ws + hh_b + xg_b);

        gru_l0_mfma<<<dim3(8), dim3(512), 0, stream>>>(
            x, wih0, whh0, bih0, bhh0, wih0r, whh0r, bih0r, bhh0r, l0h);
        xg_gemm_mfma<<<dim3(1024, 3, 1), dim3(256), 0, stream>>>(
            l0h, wih1, wih1, bih1, bih1, bhh1, bhh1, xg, xg);
        gru_l1_mfma<<<dim3(4), dim3(512), 0, stream>>>(
            xg, xg, whh1, bhh1, whh1r, bhh1r, l1h, 0);
        xg_gemm_mfma<<<dim3(1024, 3, 1), dim3(256), 0, stream>>>(
            l0h, wih1r, wih1r, bih1r, bih1r, bhh1r, bhh1r, xg, xg);
        gru_l1_mfma<<<dim3(4), dim3(512), 0, stream>>>(
            xg, xg, whh1, bhh1, whh1r, bhh1r, l1h, 1);
        fc_kernel<<<dim3((int)(nBT / 256)), dim3(256), 0, stream>>>(l1h, fcw, fcb, out);
    }
}